// Round 14
// baseline (574.960 us; speedup 1.0000x reference)
//
#include <hip/hip_runtime.h>
#include <hip/hip_bf16.h>
#include <math.h>

// BertAttention on MI355X (gfx950). fp32 I/O, bf16 MFMA internally.
// B=4 S=2048 H=1024 nH=16 dH=64.
// d_out = [output (4*2048*1024 f32)] ++ [attn_score (4*16*2048*2048 f32)]

#define BB 4
#define SS 2048
#define HH 1024
#define NHEAD 16
#define DHEAD 64

static constexpr float SCALE = 0.125f;     // 1/sqrt(64)

typedef __attribute__((ext_vector_type(8))) short s16x8;
typedef __attribute__((ext_vector_type(4))) float f32x4;
typedef __attribute__((ext_vector_type(4))) unsigned short u16x4;

__device__ __forceinline__ unsigned short f2bf(float f) {
  unsigned int u = __float_as_uint(f);
  u += 0x7fffu + ((u >> 16) & 1u);   // RNE
  return (unsigned short)(u >> 16);
}

__device__ __forceinline__ unsigned int pkbf(float lo, float hi) {
  union { __hip_bfloat162 h2; unsigned int u; } cv;
  cv.h2 = __float22bfloat162_rn(make_float2(lo, hi));   // v_cvt_pk_bf16_f32
  return cv.u;
}

__device__ __forceinline__ f32x4 MFMA(s16x8 a, s16x8 b, f32x4 c) {
  return __builtin_amdgcn_mfma_f32_16x16x32_bf16(a, b, c, 0, 0, 0);
}

__device__ __forceinline__ void async16(const void* g, void* l) {
  __builtin_amdgcn_global_load_lds(
      (const __attribute__((address_space(1))) unsigned int*)g,
      (__attribute__((address_space(3))) unsigned int*)l, 16, 0, 0);
}

// Stage 128x32 bf16 tile, source-swizzled (rule #21): LDS stays linear, the
// global column is permuted so LDS[row][c] = G[row][c ^ ((row&3)<<3)].
// Read side: kx = koff ^ ((fr&3)<<3).   (4 waves / 256 threads)
__device__ __forceinline__ void stage128x32_swz(const unsigned short* g, int ldg,
                                                unsigned short* lds, int wv, int lane) {
#pragma unroll
  for (int t = 0; t < 2; ++t) {
    int chunk = wv * 2 + t;                 // 8 chunks of 16 rows
    int row = chunk * 16 + (lane >> 2);
    int col = (((lane & 3) ^ (row & 3)) * 8);
    async16(g + (size_t)row * ldg + col, lds + chunk * 512);
  }
}

// Stage 64x64 bf16 tile with 8 waves (512 threads): one async16 per thread.
// LDS[row][c] = G[row][c ^ ((row&7)<<3)]; read kx = koff ^ ((fr&7)<<3).
__device__ __forceinline__ void stage64x64_swz8(const unsigned short* g, int ldg,
                                                unsigned short* lds, int wv, int lane) {
  int row = wv * 8 + (lane >> 3);
  int col = (((lane & 7) ^ (row & 7)) * 8);
  async16(g + (size_t)row * ldg + col, lds + wv * 512);
}

// ---------------- merged prep: hid->bf16, 4 weights->bf16, mask*-1e4 --------
__global__ void prep_all(const float* __restrict__ hid,
                         const float* __restrict__ w0, const float* __restrict__ w1,
                         const float* __restrict__ w2, const float* __restrict__ w3,
                         const float* __restrict__ mask,
                         unsigned short* __restrict__ hb,
                         unsigned short* __restrict__ wb,
                         float* __restrict__ maskv) {
  const int HID4 = (BB * SS * HH) / 4;          // 2097152 float4s
  const int W4 = (HH * HH) / 4;                 // 262144 float4s per matrix
  const int M4 = (BB * SS) / 4;                 // 2048 float4s
  const int total = HID4 + 4 * W4 + M4;
  for (int i = blockIdx.x * 256 + threadIdx.x; i < total; i += gridDim.x * 256) {
    if (i < HID4) {
      float4 v = reinterpret_cast<const float4*>(hid)[i];
      ushort4 o;
      o.x = f2bf(v.x); o.y = f2bf(v.y); o.z = f2bf(v.z); o.w = f2bf(v.w);
      reinterpret_cast<ushort4*>(hb)[i] = o;
    } else if (i < HID4 + 4 * W4) {
      int j = i - HID4;
      int z = j >> 18, k = j & (W4 - 1);        // W4 = 2^18
      const float* src = (z == 0) ? w0 : (z == 1 ? w1 : (z == 2 ? w2 : w3));
      float4 v = reinterpret_cast<const float4*>(src)[k];
      ushort4 o;
      o.x = f2bf(v.x); o.y = f2bf(v.y); o.z = f2bf(v.z); o.w = f2bf(v.w);
      reinterpret_cast<ushort4*>(wb)[z * W4 + k] = o;
    } else {
      int k = i - HID4 - 4 * W4;
      float4 v = reinterpret_cast<const float4*>(mask)[k];
      float4 o;
      o.x = v.x * -10000.0f; o.y = v.y * -10000.0f;
      o.z = v.z * -10000.0f; o.w = v.w * -10000.0f;
      reinterpret_cast<float4*>(maskv)[k] = o;
    }
  }
}

// ---------------- QKV projection: C[m,n] = sum_k X[m,k] W[n,k] + b[n] --------
// 128x128 tile, BK=32. XCD-swizzled block ids. z==2 (V) writes DIRECTLY in
// transposed Vt[b,h,d,s] layout. All outputs use NONTEMPORAL stores (R11's
// finding: streaming write-once data must not evict the L2 reuse set —
// here the X m-panels and W n-panels).
__global__ __launch_bounds__(256) void gemm_qkv(
    const unsigned short* __restrict__ X,
    const unsigned short* __restrict__ Wq, const unsigned short* __restrict__ Wk,
    const unsigned short* __restrict__ Wv,
    const float* __restrict__ bq, const float* __restrict__ bk,
    const float* __restrict__ bv,
    unsigned short* __restrict__ Qo, unsigned short* __restrict__ Ko,
    unsigned short* __restrict__ Vto) {
  __shared__ __align__(16) unsigned short As[128 * 32];
  __shared__ __align__(16) unsigned short Bs[128 * 32];
  // bijective XCD swizzle (nwg=1536, cpx=192)
  const int lin = blockIdx.x + 8 * blockIdx.y + 512 * blockIdx.z;
  const int w = (lin & 7) * 192 + (lin >> 3);
  const int bx = w & 7, by = (w >> 3) & 63, bz = w >> 9;
  const unsigned short* W = (bz == 0) ? Wq : (bz == 1 ? Wk : Wv);
  const float* bias = (bz == 0) ? bq : (bz == 1 ? bk : bv);
  const int n0 = bx * 128;
  const int m0 = by * 128;
  const int wv = threadIdx.x >> 6, lane = threadIdx.x & 63;
  const int wm = (wv >> 1) * 64, wn = (wv & 1) * 64;
  const int fr = lane & 15, koff = (lane >> 4) * 8, ko4 = (lane >> 4) * 4;
  const int kx = koff ^ ((fr & 3) << 3);     // swizzled read offset
  f32x4 acc[4][4] = {};
  for (int k0 = 0; k0 < 1024; k0 += 32) {
    __syncthreads();
    stage128x32_swz(X + (size_t)m0 * 1024 + k0, 1024, As, wv, lane);
    stage128x32_swz(W + (size_t)n0 * 1024 + k0, 1024, Bs, wv, lane);
    __syncthreads();
    s16x8 a[4], b[4];
#pragma unroll
    for (int i = 0; i < 4; ++i)
      a[i] = *reinterpret_cast<const s16x8*>(As + (wm + i * 16 + fr) * 32 + kx);
#pragma unroll
    for (int j = 0; j < 4; ++j)
      b[j] = *reinterpret_cast<const s16x8*>(Bs + (wn + j * 16 + fr) * 32 + kx);
#pragma unroll
    for (int i = 0; i < 4; ++i)
#pragma unroll
      for (int j = 0; j < 4; ++j) acc[i][j] = MFMA(a[i], b[j], acc[i][j]);
  }
  if (bz != 2) {
    unsigned short* Out = (bz == 0) ? Qo : Ko;
#pragma unroll
    for (int i = 0; i < 4; ++i) {
      int row_b = m0 + wm + i * 16 + ko4;
#pragma unroll
      for (int j = 0; j < 4; ++j) {
        int col = n0 + wn + j * 16 + fr;
        float bvv = bias[col];
#pragma unroll
        for (int r = 0; r < 4; ++r)
          __builtin_nontemporal_store(
              f2bf(acc[i][j][r] + bvv),
              Out + (size_t)(row_b + r) * 1024 + col);
      }
    }
  } else {
#pragma unroll
    for (int i = 0; i < 4; ++i) {
      int row0 = m0 + wm + i * 16 + ko4;     // global m = b*SS + s
      int bb = row0 >> 11, s0 = row0 & 2047; // 128-row tile never straddles b
#pragma unroll
      for (int j = 0; j < 4; ++j) {
        int col = n0 + wn + j * 16 + fr;
        int hh = col >> 6, dd = col & 63;
        float bvv = bias[col];
        u16x4 o;
        o.x = f2bf(acc[i][j][0] + bvv);
        o.y = f2bf(acc[i][j][1] + bvv);
        o.z = f2bf(acc[i][j][2] + bvv);
        o.w = f2bf(acc[i][j][3] + bvv);
        __builtin_nontemporal_store(
            o, reinterpret_cast<u16x4*>(
                   Vto + ((size_t)(bb * NHEAD + hh) * 64 + dd) * SS + s0));
      }
    }
  }
}

// ---------------- fused attention, swapped-QK^T, QBLK=128, 8 waves ----------
// mfma(K,Q): lane holds S[q=fr][k=j*16+ko4+reg] -> NONTEMPORAL float4 score
// stores (R11 A/B: removing nt cost +153 µs), per-lane (m,l), defer-max
// (THR=8) with tm reduce inside the rescale branch. ctx stores also nt.
__global__ __launch_bounds__(512) void attn_fused(
    const unsigned short* __restrict__ Qb, const unsigned short* __restrict__ Kb,
    const unsigned short* __restrict__ Vt, const float* __restrict__ maskv,
    float* __restrict__ scores, unsigned short* __restrict__ ctxb) {
  __shared__ __align__(16) unsigned short Ks[2][64 * 64];
  __shared__ __align__(16) unsigned short Vs[2][64 * 64];
  __shared__ __align__(16) unsigned short Ps[128 * 64];
  // bijective XCD swizzle (nwg=1024, cpx=128)
  const int lin = blockIdx.x + 16 * blockIdx.y + 256 * blockIdx.z;
  const int w = (lin & 7) * 128 + (lin >> 3);
  const int q0 = (w & 15) * 128;
  const int h = (w >> 4) & 15, b = w >> 8;
  const int wv = threadIdx.x >> 6, lane = threadIdx.x & 63;
  const int fr = lane & 15, koff = (lane >> 4) * 8, ko4 = (lane >> 4) * 4;
  const int kx = koff ^ ((fr & 7) << 3);
  const int kx2 = (koff + 32) ^ ((fr & 7) << 3);
  const float* mvb = maskv + b * 2048;
  const unsigned short* qp =
      Qb + ((size_t)b * SS + q0 + wv * 16 + fr) * HH + h * 64 + koff;
  s16x8 aq0 = *reinterpret_cast<const s16x8*>(qp);
  s16x8 aq1 = *reinterpret_cast<const s16x8*>(qp + 32);
  const unsigned short* kbase = Kb + (size_t)b * SS * HH + h * 64;       // ld=HH
  const unsigned short* vbase = Vt + (size_t)(b * NHEAD + h) * 64 * SS;  // ld=SS
  float mr = -1e30f, lr = 0.f;
  f32x4 accpv[4] = {};
  const size_t srow = (size_t)(b * NHEAD + h) * 2048;
  float* srowp = scores + (srow + q0 + wv * 16 + fr) * 2048 + ko4;

  stage64x64_swz8(kbase, HH, Ks[0], wv, lane);
  stage64x64_swz8(vbase, SS, Vs[0], wv, lane);
  int cur = 0;
  for (int kt = 0; kt < 32; ++kt) {
    __syncthreads();   // buf[cur] staged & drained; prev PV done with buf[cur^1]
    if (kt + 1 < 32) {
      stage64x64_swz8(kbase + (size_t)(kt + 1) * 64 * HH, HH, Ks[cur ^ 1], wv, lane);
      stage64x64_swz8(vbase + (kt + 1) * 64, SS, Vs[cur ^ 1], wv, lane);
    }
    // ---- QK^T swapped: A=K rows (k), B=Q rows (q, this wave's 16) ----
    const unsigned short* kp = Ks[cur];
    f32x4 acc[4] = {};
#pragma unroll
    for (int j = 0; j < 4; ++j) {
      const unsigned short* rp = kp + (j * 16 + fr) * 64;
      s16x8 k0 = *reinterpret_cast<const s16x8*>(rp + kx);
      s16x8 k1 = *reinterpret_cast<const s16x8*>(rp + kx2);
      acc[j] = MFMA(k0, aq0, acc[j]);
      acc[j] = MFMA(k1, aq1, acc[j]);
    }
    // ---- scale + mask + nt float4 score store; per-lane partial max ----
    const int kb = kt * 64;
    float sv[4][4];
    float tm = -1e30f;
#pragma unroll
    for (int j = 0; j < 4; ++j) {
      float4 mk = *reinterpret_cast<const float4*>(mvb + kb + j * 16 + ko4);
      f32x4 s4 = acc[j] * SCALE;
      s4[0] += mk.x; s4[1] += mk.y; s4[2] += mk.z; s4[3] += mk.w;
      __builtin_nontemporal_store(s4, reinterpret_cast<f32x4*>(srowp + kb + j * 16));
      sv[j][0] = s4[0]; sv[j][1] = s4[1]; sv[j][2] = s4[2]; sv[j][3] = s4[3];
      tm = fmaxf(tm, fmaxf(fmaxf(s4[0], s4[1]), fmaxf(s4[2], s4[3])));
    }
    // ---- defer-max rescale (THR=8); per-lane check == row-max check ----
    if (!__all(tm <= mr + 8.0f)) {
      tm = fmaxf(tm, __shfl_xor(tm, 16, 64));
      tm = fmaxf(tm, __shfl_xor(tm, 32, 64));
      float nm = fmaxf(mr, tm);
      float f = __expf(mr - nm);
      lr *= f;
      float fb[4];
#pragma unroll
      for (int r = 0; r < 4; ++r) fb[r] = __shfl(f, ko4 + r, 64);
#pragma unroll
      for (int jd = 0; jd < 4; ++jd)
#pragma unroll
        for (int r = 0; r < 4; ++r) accpv[jd][r] *= fb[r];
      mr = nm;
    }
    // ---- P = exp(S - m), row-sum, cvt_pk pack to LDS (wave-private rows) ----
    float psum = 0.f;
    unsigned int pw[4][2];
#pragma unroll
    for (int j = 0; j < 4; ++j) {
      float p0 = __expf(sv[j][0] - mr), p1 = __expf(sv[j][1] - mr);
      float p2 = __expf(sv[j][2] - mr), p3 = __expf(sv[j][3] - mr);
      psum += (p0 + p1) + (p2 + p3);
      pw[j][0] = pkbf(p0, p1);
      pw[j][1] = pkbf(p2, p3);
    }
    psum += __shfl_xor(psum, 16, 64);
    psum += __shfl_xor(psum, 32, 64);
    lr += psum;
    {
      const int qloc = wv * 16 + fr;
      const int xr = (fr & 7) << 3;
      unsigned short* pbase = Ps + qloc * 64;
#pragma unroll
      for (int j = 0; j < 4; ++j) {
        uint2 w2; w2.x = pw[j][0]; w2.y = pw[j][1];
        *reinterpret_cast<uint2*>(pbase + ((j * 16 + ko4) ^ xr)) = w2;
      }
    }
    // ---- PV (Ps rows are this wave's own; no barrier needed) ----
    const unsigned short* pr = Ps + (wv * 16 + fr) * 64;
    s16x8 pa0 = *reinterpret_cast<const s16x8*>(pr + kx);
    s16x8 pa1 = *reinterpret_cast<const s16x8*>(pr + kx2);
    const unsigned short* vp = Vs[cur];
#pragma unroll
    for (int j = 0; j < 4; ++j) {
      const unsigned short* rp = vp + (j * 16 + fr) * 64;
      accpv[j] = MFMA(pa0, *reinterpret_cast<const s16x8*>(rp + kx), accpv[j]);
      accpv[j] = MFMA(pa1, *reinterpret_cast<const s16x8*>(rp + kx2), accpv[j]);
    }
    cur ^= 1;
  }
  // ---- epilogue (nt ctx stores) ----
  float il = 1.0f / lr;
  float ilb[4];
#pragma unroll
  for (int r = 0; r < 4; ++r) ilb[r] = __shfl(il, ko4 + r, 64);
#pragma unroll
  for (int j = 0; j < 4; ++j) {
#pragma unroll
    for (int r = 0; r < 4; ++r) {
      int ql = wv * 16 + ko4 + r;
      int d = j * 16 + fr;
      __builtin_nontemporal_store(
          f2bf(accpv[j][r] * ilb[r]),
          ctxb + ((size_t)b * SS + q0 + ql) * HH + h * 64 + d);
    }
  }
}

// ---------------- out-proj + bias + residual (BK=32) ----------------
__global__ __launch_bounds__(256) void gemm_out(
    const unsigned short* __restrict__ Cx, const unsigned short* __restrict__ Wo,
    const float* __restrict__ bo, const float* __restrict__ hid,
    float* __restrict__ y) {
  __shared__ __align__(16) unsigned short As[128 * 32];
  __shared__ __align__(16) unsigned short Bs[128 * 32];
  // bijective XCD swizzle (nwg=512, cpx=64)
  const int lin = blockIdx.x + 8 * blockIdx.y;
  const int w = (lin & 7) * 64 + (lin >> 3);
  const int n0 = (w & 7) * 128;
  const int m0 = (w >> 3) * 128;
  const int wv = threadIdx.x >> 6, lane = threadIdx.x & 63;
  const int wm = (wv >> 1) * 64, wn = (wv & 1) * 64;
  const int fr = lane & 15, koff = (lane >> 4) * 8;
  const int kx = koff ^ ((fr & 3) << 3);
  f32x4 acc[4][4] = {};
  for (int k0 = 0; k0 < 1024; k0 += 32) {
    __syncthreads();
    stage128x32_swz(Cx + (size_t)m0 * 1024 + k0, 1024, As, wv, lane);
    stage128x32_swz(Wo + (size_t)n0 * 1024 + k0, 1024, Bs, wv, lane);
    __syncthreads();
    s16x8 a[4], b[4];
#pragma unroll
    for (int i = 0; i < 4; ++i)
      a[i] = *reinterpret_cast<const s16x8*>(As + (wm + i * 16 + fr) * 32 + kx);
#pragma unroll
    for (int j = 0; j < 4; ++j)
      b[j] = *reinterpret_cast<const s16x8*>(Bs + (wn + j * 16 + fr) * 32 + kx);
#pragma unroll
    for (int i = 0; i < 4; ++i)
#pragma unroll
      for (int j = 0; j < 4; ++j) acc[i][j] = MFMA(a[i], b[j], acc[i][j]);
  }
#pragma unroll
  for (int i = 0; i < 4; ++i) {
    int row_b = m0 + wm + i * 16 + ((lane >> 4) << 2);
#pragma unroll
    for (int j = 0; j < 4; ++j) {
      int col = n0 + wn + j * 16 + fr;
      float bvv = bo[col];
#pragma unroll
      for (int r = 0; r < 4; ++r) {
        size_t idx = (size_t)(row_b + r) * 1024 + col;
        __builtin_nontemporal_store(acc[i][j][r] + bvv + hid[idx], y + idx);
      }
    }
  }
}

// ---------------- in-place LayerNorm over last dim (1024) ----------------
__global__ __launch_bounds__(256) void layernorm_inplace(
    float* __restrict__ y, const float* __restrict__ gamma,
    const float* __restrict__ beta) {
  const int row = blockIdx.x;
  float* p = y + (size_t)row * 1024;
  float4 v = reinterpret_cast<const float4*>(p)[threadIdx.x];
  float s = v.x + v.y + v.z + v.w;
  float ss = v.x * v.x + v.y * v.y + v.z * v.z + v.w * v.w;
#pragma unroll
  for (int off = 1; off < 64; off <<= 1) {
    s += __shfl_xor(s, off, 64);
    ss += __shfl_xor(ss, off, 64);
  }
  __shared__ float sa[4], sb[4];
  const int wv = threadIdx.x >> 6, lane = threadIdx.x & 63;
  if (lane == 0) { sa[wv] = s; sb[wv] = ss; }
  __syncthreads();
  s = sa[0] + sa[1] + sa[2] + sa[3];
  ss = sb[0] + sb[1] + sb[2] + sb[3];
  const float mean = s * (1.0f / 1024.0f);
  const float var = ss * (1.0f / 1024.0f) - mean * mean;
  const float rstd = rsqrtf(var + 1e-5f);
  float4 g = reinterpret_cast<const float4*>(gamma)[threadIdx.x];
  float4 be = reinterpret_cast<const float4*>(beta)[threadIdx.x];
  float4 o;
  o.x = (v.x - mean) * rstd * g.x + be.x;
  o.y = (v.y - mean) * rstd * g.y + be.y;
  o.z = (v.z - mean) * rstd * g.z + be.z;
  o.w = (v.w - mean) * rstd * g.w + be.w;
  reinterpret_cast<float4*>(p)[threadIdx.x] = o;
}

extern "C" void kernel_launch(void* const* d_in, const int* in_sizes, int n_in,
                              void* d_out, int out_size, void* d_ws,
                              size_t ws_size, hipStream_t stream) {
  const float* hid   = (const float*)d_in[0];
  const float* mask  = (const float*)d_in[1];
  const float* Wq    = (const float*)d_in[2];
  const float* bq    = (const float*)d_in[3];
  const float* Wk    = (const float*)d_in[4];
  const float* bk    = (const float*)d_in[5];
  const float* Wv    = (const float*)d_in[6];
  const float* bv    = (const float*)d_in[7];
  const float* Wo    = (const float*)d_in[8];
  const float* bo    = (const float*)d_in[9];
  const float* gamma = (const float*)d_in[10];
  const float* beta  = (const float*)d_in[11];

  float* outp = (float*)d_out;                       // [4,2048,1024]
  float* scores = outp + (size_t)BB * SS * HH;       // [4,16,2048,2048]

  char* ws = (char*)d_ws;
  size_t off = 0;
  unsigned short* hb  = (unsigned short*)(ws + off); off += (size_t)BB * SS * HH * 2;
  unsigned short* wqb = (unsigned short*)(ws + off); off += (size_t)HH * HH * 2;
  unsigned short* wkb = (unsigned short*)(ws + off); off += (size_t)HH * HH * 2;
  unsigned short* wvb = (unsigned short*)(ws + off); off += (size_t)HH * HH * 2;
  unsigned short* wob = (unsigned short*)(ws + off); off += (size_t)HH * HH * 2;
  unsigned short* Qb  = (unsigned short*)(ws + off); off += (size_t)BB * SS * HH * 2;
  unsigned short* Kb  = (unsigned short*)(ws + off); off += (size_t)BB * SS * HH * 2;
  unsigned short* Vt  = (unsigned short*)(ws + off); off += (size_t)BB * SS * HH * 2;
  unsigned short* ctx = (unsigned short*)(ws + off); off += (size_t)BB * SS * HH * 2;
  float* maskv = (float*)(ws + off); off += (size_t)BB * SS * 4;

  prep_all<<<2048, 256, 0, stream>>>(hid, Wq, Wk, Wv, Wo, mask, hb, wqb, maskv);

  gemm_qkv<<<dim3(8, 64, 3), 256, 0, stream>>>(hb, wqb, wkb, wvb, bq, bk, bv,
                                               Qb, Kb, Vt);
  attn_fused<<<dim3(16, 16, 4), 512, 0, stream>>>(Qb, Kb, Vt, maskv, scores, ctx);
  gemm_out<<<dim3(8, 64), 256, 0, stream>>>(ctx, wob, bo, hid, outp);
  layernorm_inplace<<<BB * SS, 256, 0, stream>>>(outp, gamma, beta);
}

// Round 15
// 431.792 us; speedup vs baseline: 1.3316x; 1.3316x over previous
//
#include <hip/hip_runtime.h>
#include <hip/hip_bf16.h>
#include <math.h>

// BertAttention on MI355X (gfx950). fp32 I/O, bf16 MFMA internally.
// B=4 S=2048 H=1024 nH=16 dH=64.
// d_out = [output (4*2048*1024 f32)] ++ [attn_score (4*16*2048*2048 f32)]
// R15 = R12-exact revert (best: 432.8 µs). R13/R14 A/B proved nt stores are
// ONLY safe for full-line-coalesced wide stores (f32x4 scores); scalar bf16
// nt stores bypass L2 write-combining -> partial-line RMW, +142 µs.

#define BB 4
#define SS 2048
#define HH 1024
#define NHEAD 16
#define DHEAD 64

static constexpr float SCALE = 0.125f;     // 1/sqrt(64)

typedef __attribute__((ext_vector_type(8))) short s16x8;
typedef __attribute__((ext_vector_type(4))) float f32x4;

__device__ __forceinline__ unsigned short f2bf(float f) {
  unsigned int u = __float_as_uint(f);
  u += 0x7fffu + ((u >> 16) & 1u);   // RNE
  return (unsigned short)(u >> 16);
}

__device__ __forceinline__ unsigned int pkbf(float lo, float hi) {
  union { __hip_bfloat162 h2; unsigned int u; } cv;
  cv.h2 = __float22bfloat162_rn(make_float2(lo, hi));   // v_cvt_pk_bf16_f32
  return cv.u;
}

__device__ __forceinline__ f32x4 MFMA(s16x8 a, s16x8 b, f32x4 c) {
  return __builtin_amdgcn_mfma_f32_16x16x32_bf16(a, b, c, 0, 0, 0);
}

__device__ __forceinline__ void async16(const void* g, void* l) {
  __builtin_amdgcn_global_load_lds(
      (const __attribute__((address_space(1))) unsigned int*)g,
      (__attribute__((address_space(3))) unsigned int*)l, 16, 0, 0);
}

// Stage 128x32 bf16 tile, source-swizzled (rule #21): LDS stays linear, the
// global column is permuted so LDS[row][c] = G[row][c ^ ((row&3)<<3)].
// Read side: kx = koff ^ ((fr&3)<<3).   (4 waves / 256 threads)
__device__ __forceinline__ void stage128x32_swz(const unsigned short* g, int ldg,
                                                unsigned short* lds, int wv, int lane) {
#pragma unroll
  for (int t = 0; t < 2; ++t) {
    int chunk = wv * 2 + t;                 // 8 chunks of 16 rows
    int row = chunk * 16 + (lane >> 2);
    int col = (((lane & 3) ^ (row & 3)) * 8);
    async16(g + (size_t)row * ldg + col, lds + chunk * 512);
  }
}

// Stage 64x64 bf16 tile with 8 waves (512 threads): one async16 per thread.
// LDS[row][c] = G[row][c ^ ((row&7)<<3)]; read kx = koff ^ ((fr&7)<<3).
__device__ __forceinline__ void stage64x64_swz8(const unsigned short* g, int ldg,
                                                unsigned short* lds, int wv, int lane) {
  int row = wv * 8 + (lane >> 3);
  int col = (((lane & 7) ^ (row & 7)) * 8);
  async16(g + (size_t)row * ldg + col, lds + wv * 512);
}

// ---------------- merged prep: hid->bf16, 4 weights->bf16, mask*-1e4 --------
__global__ void prep_all(const float* __restrict__ hid,
                         const float* __restrict__ w0, const float* __restrict__ w1,
                         const float* __restrict__ w2, const float* __restrict__ w3,
                         const float* __restrict__ mask,
                         unsigned short* __restrict__ hb,
                         unsigned short* __restrict__ wb,
                         float* __restrict__ maskv) {
  const int HID4 = (BB * SS * HH) / 4;          // 2097152 float4s
  const int W4 = (HH * HH) / 4;                 // 262144 float4s per matrix
  const int M4 = (BB * SS) / 4;                 // 2048 float4s
  const int total = HID4 + 4 * W4 + M4;
  for (int i = blockIdx.x * 256 + threadIdx.x; i < total; i += gridDim.x * 256) {
    if (i < HID4) {
      float4 v = reinterpret_cast<const float4*>(hid)[i];
      ushort4 o;
      o.x = f2bf(v.x); o.y = f2bf(v.y); o.z = f2bf(v.z); o.w = f2bf(v.w);
      reinterpret_cast<ushort4*>(hb)[i] = o;
    } else if (i < HID4 + 4 * W4) {
      int j = i - HID4;
      int z = j >> 18, k = j & (W4 - 1);        // W4 = 2^18
      const float* src = (z == 0) ? w0 : (z == 1 ? w1 : (z == 2 ? w2 : w3));
      float4 v = reinterpret_cast<const float4*>(src)[k];
      ushort4 o;
      o.x = f2bf(v.x); o.y = f2bf(v.y); o.z = f2bf(v.z); o.w = f2bf(v.w);
      reinterpret_cast<ushort4*>(wb)[z * W4 + k] = o;
    } else {
      int k = i - HID4 - 4 * W4;
      float4 v = reinterpret_cast<const float4*>(mask)[k];
      float4 o;
      o.x = v.x * -10000.0f; o.y = v.y * -10000.0f;
      o.z = v.z * -10000.0f; o.w = v.w * -10000.0f;
      reinterpret_cast<float4*>(maskv)[k] = o;
    }
  }
}

// ---------------- QKV projection: C[m,n] = sum_k X[m,k] W[n,k] + b[n] --------
// 128x128 tile, BK=32. XCD-swizzled block ids. z==2 (V) writes DIRECTLY in
// transposed Vt[b,h,d,s] layout from the accumulators (8B/lane stores, the
// i-loop completes 128B-contiguous row segments) -> no transpose kernel.
__global__ __launch_bounds__(256) void gemm_qkv(
    const unsigned short* __restrict__ X,
    const unsigned short* __restrict__ Wq, const unsigned short* __restrict__ Wk,
    const unsigned short* __restrict__ Wv,
    const float* __restrict__ bq, const float* __restrict__ bk,
    const float* __restrict__ bv,
    unsigned short* __restrict__ Qo, unsigned short* __restrict__ Ko,
    unsigned short* __restrict__ Vto) {
  __shared__ __align__(16) unsigned short As[128 * 32];
  __shared__ __align__(16) unsigned short Bs[128 * 32];
  // bijective XCD swizzle (nwg=1536, cpx=192)
  const int lin = blockIdx.x + 8 * blockIdx.y + 512 * blockIdx.z;
  const int w = (lin & 7) * 192 + (lin >> 3);
  const int bx = w & 7, by = (w >> 3) & 63, bz = w >> 9;
  const unsigned short* W = (bz == 0) ? Wq : (bz == 1 ? Wk : Wv);
  const float* bias = (bz == 0) ? bq : (bz == 1 ? bk : bv);
  const int n0 = bx * 128;
  const int m0 = by * 128;
  const int wv = threadIdx.x >> 6, lane = threadIdx.x & 63;
  const int wm = (wv >> 1) * 64, wn = (wv & 1) * 64;
  const int fr = lane & 15, koff = (lane >> 4) * 8, ko4 = (lane >> 4) * 4;
  const int kx = koff ^ ((fr & 3) << 3);     // swizzled read offset
  f32x4 acc[4][4] = {};
  for (int k0 = 0; k0 < 1024; k0 += 32) {
    __syncthreads();
    stage128x32_swz(X + (size_t)m0 * 1024 + k0, 1024, As, wv, lane);
    stage128x32_swz(W + (size_t)n0 * 1024 + k0, 1024, Bs, wv, lane);
    __syncthreads();
    s16x8 a[4], b[4];
#pragma unroll
    for (int i = 0; i < 4; ++i)
      a[i] = *reinterpret_cast<const s16x8*>(As + (wm + i * 16 + fr) * 32 + kx);
#pragma unroll
    for (int j = 0; j < 4; ++j)
      b[j] = *reinterpret_cast<const s16x8*>(Bs + (wn + j * 16 + fr) * 32 + kx);
#pragma unroll
    for (int i = 0; i < 4; ++i)
#pragma unroll
      for (int j = 0; j < 4; ++j) acc[i][j] = MFMA(a[i], b[j], acc[i][j]);
  }
  if (bz != 2) {
    unsigned short* Out = (bz == 0) ? Qo : Ko;
#pragma unroll
    for (int i = 0; i < 4; ++i) {
      int row_b = m0 + wm + i * 16 + ko4;
#pragma unroll
      for (int j = 0; j < 4; ++j) {
        int col = n0 + wn + j * 16 + fr;
        float bvv = bias[col];
#pragma unroll
        for (int r = 0; r < 4; ++r)
          Out[(size_t)(row_b + r) * 1024 + col] = f2bf(acc[i][j][r] + bvv);
      }
    }
  } else {
#pragma unroll
    for (int i = 0; i < 4; ++i) {
      int row0 = m0 + wm + i * 16 + ko4;     // global m = b*SS + s
      int bb = row0 >> 11, s0 = row0 & 2047; // 128-row tile never straddles b
#pragma unroll
      for (int j = 0; j < 4; ++j) {
        int col = n0 + wn + j * 16 + fr;
        int hh = col >> 6, dd = col & 63;
        float bvv = bias[col];
        ushort4 o;
        o.x = f2bf(acc[i][j][0] + bvv);
        o.y = f2bf(acc[i][j][1] + bvv);
        o.z = f2bf(acc[i][j][2] + bvv);
        o.w = f2bf(acc[i][j][3] + bvv);
        *reinterpret_cast<ushort4*>(
            Vto + ((size_t)(bb * NHEAD + hh) * 64 + dd) * SS + s0) = o;
      }
    }
  }
}

// ---------------- fused attention, swapped-QK^T, QBLK=128, 8 waves ----------
// mfma(K,Q): lane holds S[q=fr][k=j*16+ko4+reg] -> NONTEMPORAL float4 score
// stores (R11 A/B: removing nt cost +153 µs — nt protects L2 from the 1.07 GB
// score stream; K/V panels shared by 16 q-blocks stay resident), per-lane
// (m,l), defer-max (THR=8) with tm reduce inside the rescale branch.
__global__ __launch_bounds__(512) void attn_fused(
    const unsigned short* __restrict__ Qb, const unsigned short* __restrict__ Kb,
    const unsigned short* __restrict__ Vt, const float* __restrict__ maskv,
    float* __restrict__ scores, unsigned short* __restrict__ ctxb) {
  __shared__ __align__(16) unsigned short Ks[2][64 * 64];
  __shared__ __align__(16) unsigned short Vs[2][64 * 64];
  __shared__ __align__(16) unsigned short Ps[128 * 64];
  // bijective XCD swizzle (nwg=1024, cpx=128)
  const int lin = blockIdx.x + 16 * blockIdx.y + 256 * blockIdx.z;
  const int w = (lin & 7) * 128 + (lin >> 3);
  const int q0 = (w & 15) * 128;
  const int h = (w >> 4) & 15, b = w >> 8;
  const int wv = threadIdx.x >> 6, lane = threadIdx.x & 63;
  const int fr = lane & 15, koff = (lane >> 4) * 8, ko4 = (lane >> 4) * 4;
  const int kx = koff ^ ((fr & 7) << 3);
  const int kx2 = (koff + 32) ^ ((fr & 7) << 3);
  const float* mvb = maskv + b * 2048;
  const unsigned short* qp =
      Qb + ((size_t)b * SS + q0 + wv * 16 + fr) * HH + h * 64 + koff;
  s16x8 aq0 = *reinterpret_cast<const s16x8*>(qp);
  s16x8 aq1 = *reinterpret_cast<const s16x8*>(qp + 32);
  const unsigned short* kbase = Kb + (size_t)b * SS * HH + h * 64;       // ld=HH
  const unsigned short* vbase = Vt + (size_t)(b * NHEAD + h) * 64 * SS;  // ld=SS
  float mr = -1e30f, lr = 0.f;
  f32x4 accpv[4] = {};
  const size_t srow = (size_t)(b * NHEAD + h) * 2048;
  float* srowp = scores + (srow + q0 + wv * 16 + fr) * 2048 + ko4;

  stage64x64_swz8(kbase, HH, Ks[0], wv, lane);
  stage64x64_swz8(vbase, SS, Vs[0], wv, lane);
  int cur = 0;
  for (int kt = 0; kt < 32; ++kt) {
    __syncthreads();   // buf[cur] staged & drained; prev PV done with buf[cur^1]
    if (kt + 1 < 32) {
      stage64x64_swz8(kbase + (size_t)(kt + 1) * 64 * HH, HH, Ks[cur ^ 1], wv, lane);
      stage64x64_swz8(vbase + (kt + 1) * 64, SS, Vs[cur ^ 1], wv, lane);
    }
    // ---- QK^T swapped: A=K rows (k), B=Q rows (q, this wave's 16) ----
    const unsigned short* kp = Ks[cur];
    f32x4 acc[4] = {};
#pragma unroll
    for (int j = 0; j < 4; ++j) {
      const unsigned short* rp = kp + (j * 16 + fr) * 64;
      s16x8 k0 = *reinterpret_cast<const s16x8*>(rp + kx);
      s16x8 k1 = *reinterpret_cast<const s16x8*>(rp + kx2);
      acc[j] = MFMA(k0, aq0, acc[j]);
      acc[j] = MFMA(k1, aq1, acc[j]);
    }
    // ---- scale + mask + nt float4 score store; per-lane partial max ----
    const int kb = kt * 64;
    float sv[4][4];
    float tm = -1e30f;
#pragma unroll
    for (int j = 0; j < 4; ++j) {
      float4 mk = *reinterpret_cast<const float4*>(mvb + kb + j * 16 + ko4);
      f32x4 s4 = acc[j] * SCALE;
      s4[0] += mk.x; s4[1] += mk.y; s4[2] += mk.z; s4[3] += mk.w;
      __builtin_nontemporal_store(s4, reinterpret_cast<f32x4*>(srowp + kb + j * 16));
      sv[j][0] = s4[0]; sv[j][1] = s4[1]; sv[j][2] = s4[2]; sv[j][3] = s4[3];
      tm = fmaxf(tm, fmaxf(fmaxf(s4[0], s4[1]), fmaxf(s4[2], s4[3])));
    }
    // ---- defer-max rescale (THR=8); per-lane check == row-max check ----
    if (!__all(tm <= mr + 8.0f)) {
      tm = fmaxf(tm, __shfl_xor(tm, 16, 64));
      tm = fmaxf(tm, __shfl_xor(tm, 32, 64));
      float nm = fmaxf(mr, tm);
      float f = __expf(mr - nm);
      lr *= f;
      float fb[4];
#pragma unroll
      for (int r = 0; r < 4; ++r) fb[r] = __shfl(f, ko4 + r, 64);
#pragma unroll
      for (int jd = 0; jd < 4; ++jd)
#pragma unroll
        for (int r = 0; r < 4; ++r) accpv[jd][r] *= fb[r];
      mr = nm;
    }
    // ---- P = exp(S - m), row-sum, cvt_pk pack to LDS (wave-private rows) ----
    float psum = 0.f;
    unsigned int pw[4][2];
#pragma unroll
    for (int j = 0; j < 4; ++j) {
      float p0 = __expf(sv[j][0] - mr), p1 = __expf(sv[j][1] - mr);
      float p2 = __expf(sv[j][2] - mr), p3 = __expf(sv[j][3] - mr);
      psum += (p0 + p1) + (p2 + p3);
      pw[j][0] = pkbf(p0, p1);
      pw[j][1] = pkbf(p2, p3);
    }
    psum += __shfl_xor(psum, 16, 64);
    psum += __shfl_xor(psum, 32, 64);
    lr += psum;
    {
      const int qloc = wv * 16 + fr;
      const int xr = (fr & 7) << 3;
      unsigned short* pbase = Ps + qloc * 64;
#pragma unroll
      for (int j = 0; j < 4; ++j) {
        uint2 w2; w2.x = pw[j][0]; w2.y = pw[j][1];
        *reinterpret_cast<uint2*>(pbase + ((j * 16 + ko4) ^ xr)) = w2;
      }
    }
    // ---- PV (Ps rows are this wave's own; no barrier needed) ----
    const unsigned short* pr = Ps + (wv * 16 + fr) * 64;
    s16x8 pa0 = *reinterpret_cast<const s16x8*>(pr + kx);
    s16x8 pa1 = *reinterpret_cast<const s16x8*>(pr + kx2);
    const unsigned short* vp = Vs[cur];
#pragma unroll
    for (int j = 0; j < 4; ++j) {
      const unsigned short* rp = vp + (j * 16 + fr) * 64;
      accpv[j] = MFMA(pa0, *reinterpret_cast<const s16x8*>(rp + kx), accpv[j]);
      accpv[j] = MFMA(pa1, *reinterpret_cast<const s16x8*>(rp + kx2), accpv[j]);
    }
    cur ^= 1;
  }
  // ---- epilogue ----
  float il = 1.0f / lr;
  float ilb[4];
#pragma unroll
  for (int r = 0; r < 4; ++r) ilb[r] = __shfl(il, ko4 + r, 64);
#pragma unroll
  for (int j = 0; j < 4; ++j) {
#pragma unroll
    for (int r = 0; r < 4; ++r) {
      int ql = wv * 16 + ko4 + r;
      int d = j * 16 + fr;
      ctxb[((size_t)b * SS + q0 + ql) * HH + h * 64 + d] =
          f2bf(accpv[j][r] * ilb[r]);
    }
  }
}

// ---------------- out-proj + bias + residual (BK=32) ----------------
__global__ __launch_bounds__(256) void gemm_out(
    const unsigned short* __restrict__ Cx, const unsigned short* __restrict__ Wo,
    const float* __restrict__ bo, const float* __restrict__ hid,
    float* __restrict__ y) {
  __shared__ __align__(16) unsigned short As[128 * 32];
  __shared__ __align__(16) unsigned short Bs[128 * 32];
  // bijective XCD swizzle (nwg=512, cpx=64)
  const int lin = blockIdx.x + 8 * blockIdx.y;
  const int w = (lin & 7) * 64 + (lin >> 3);
  const int n0 = (w & 7) * 128;
  const int m0 = (w >> 3) * 128;
  const int wv = threadIdx.x >> 6, lane = threadIdx.x & 63;
  const int wm = (wv >> 1) * 64, wn = (wv & 1) * 64;
  const int fr = lane & 15, koff = (lane >> 4) * 8;
  const int kx = koff ^ ((fr & 3) << 3);
  f32x4 acc[4][4] = {};
  for (int k0 = 0; k0 < 1024; k0 += 32) {
    __syncthreads();
    stage128x32_swz(Cx + (size_t)m0 * 1024 + k0, 1024, As, wv, lane);
    stage128x32_swz(Wo + (size_t)n0 * 1024 + k0, 1024, Bs, wv, lane);
    __syncthreads();
    s16x8 a[4], b[4];
#pragma unroll
    for (int i = 0; i < 4; ++i)
      a[i] = *reinterpret_cast<const s16x8*>(As + (wm + i * 16 + fr) * 32 + kx);
#pragma unroll
    for (int j = 0; j < 4; ++j)
      b[j] = *reinterpret_cast<const s16x8*>(Bs + (wn + j * 16 + fr) * 32 + kx);
#pragma unroll
    for (int i = 0; i < 4; ++i)
#pragma unroll
      for (int j = 0; j < 4; ++j) acc[i][j] = MFMA(a[i], b[j], acc[i][j]);
  }
#pragma unroll
  for (int i = 0; i < 4; ++i) {
    int row_b = m0 + wm + i * 16 + ((lane >> 4) << 2);
#pragma unroll
    for (int j = 0; j < 4; ++j) {
      int col = n0 + wn + j * 16 + fr;
      float bvv = bo[col];
#pragma unroll
      for (int r = 0; r < 4; ++r) {
        size_t idx = (size_t)(row_b + r) * 1024 + col;
        y[idx] = acc[i][j][r] + bvv + hid[idx];
      }
    }
  }
}

// ---------------- in-place LayerNorm over last dim (1024) ----------------
__global__ __launch_bounds__(256) void layernorm_inplace(
    float* __restrict__ y, const float* __restrict__ gamma,
    const float* __restrict__ beta) {
  const int row = blockIdx.x;
  float* p = y + (size_t)row * 1024;
  float4 v = reinterpret_cast<const float4*>(p)[threadIdx.x];
  float s = v.x + v.y + v.z + v.w;
  float ss = v.x * v.x + v.y * v.y + v.z * v.z + v.w * v.w;
#pragma unroll
  for (int off = 1; off < 64; off <<= 1) {
    s += __shfl_xor(s, off, 64);
    ss += __shfl_xor(ss, off, 64);
  }
  __shared__ float sa[4], sb[4];
  const int wv = threadIdx.x >> 6, lane = threadIdx.x & 63;
  if (lane == 0) { sa[wv] = s; sb[wv] = ss; }
  __syncthreads();
  s = sa[0] + sa[1] + sa[2] + sa[3];
  ss = sb[0] + sb[1] + sb[2] + sb[3];
  const float mean = s * (1.0f / 1024.0f);
  const float var = ss * (1.0f / 1024.0f) - mean * mean;
  const float rstd = rsqrtf(var + 1e-5f);
  float4 g = reinterpret_cast<const float4*>(gamma)[threadIdx.x];
  float4 be = reinterpret_cast<const float4*>(beta)[threadIdx.x];
  float4 o;
  o.x = (v.x - mean) * rstd * g.x + be.x;
  o.y = (v.y - mean) * rstd * g.y + be.y;
  o.z = (v.z - mean) * rstd * g.z + be.z;
  o.w = (v.w - mean) * rstd * g.w + be.w;
  reinterpret_cast<float4*>(p)[threadIdx.x] = o;
}

extern "C" void kernel_launch(void* const* d_in, const int* in_sizes, int n_in,
                              void* d_out, int out_size, void* d_ws,
                              size_t ws_size, hipStream_t stream) {
  const float* hid   = (const float*)d_in[0];
  const float* mask  = (const float*)d_in[1];
  const float* Wq    = (const float*)d_in[2];
  const float* bq    = (const float*)d_in[3];
  const float* Wk    = (const float*)d_in[4];
  const float* bk    = (const float*)d_in[5];
  const float* Wv    = (const float*)d_in[6];
  const float* bv    = (const float*)d_in[7];
  const float* Wo    = (const float*)d_in[8];
  const float* bo    = (const float*)d_in[9];
  const float* gamma = (const float*)d_in[10];
  const float* beta  = (const float*)d_in[11];

  float* outp = (float*)d_out;                       // [4,2048,1024]
  float* scores = outp + (size_t)BB * SS * HH;       // [4,16,2048,2048]

  char* ws = (char*)d_ws;
  size_t off = 0;
  unsigned short* hb  = (unsigned short*)(ws + off); off += (size_t)BB * SS * HH * 2;
  unsigned short* wqb = (unsigned short*)(ws + off); off += (size_t)HH * HH * 2;
  unsigned short* wkb = (unsigned short*)(ws + off); off += (size_t)HH * HH * 2;
  unsigned short* wvb = (unsigned short*)(ws + off); off += (size_t)HH * HH * 2;
  unsigned short* wob = (unsigned short*)(ws + off); off += (size_t)HH * HH * 2;
  unsigned short* Qb  = (unsigned short*)(ws + off); off += (size_t)BB * SS * HH * 2;
  unsigned short* Kb  = (unsigned short*)(ws + off); off += (size_t)BB * SS * HH * 2;
  unsigned short* Vt  = (unsigned short*)(ws + off); off += (size_t)BB * SS * HH * 2;
  unsigned short* ctx = (unsigned short*)(ws + off); off += (size_t)BB * SS * HH * 2;
  float* maskv = (float*)(ws + off); off += (size_t)BB * SS * 4;

  prep_all<<<2048, 256, 0, stream>>>(hid, Wq, Wk, Wv, Wo, mask, hb, wqb, maskv);

  gemm_qkv<<<dim3(8, 64, 3), 256, 0, stream>>>(hb, wqb, wkb, wvb, bq, bk, bv,
                                               Qb, Kb, Vt);
  attn_fused<<<dim3(16, 16, 4), 512, 0, stream>>>(Qb, Kb, Vt, maskv, scores, ctx);
  gemm_out<<<dim3(8, 64), 256, 0, stream>>>(ctx, wob, bo, hid, outp);
  layernorm_inplace<<<BB * SS, 256, 0, stream>>>(outp, gamma, beta);
}